// Round 1
// baseline (83.992 us; speedup 1.0000x reference)
//
#include <hip/hip_runtime.h>

// SNN autoencoder collapses to: m_e = x @ enc_w ; m_d = m_e @ dec_w
// (spike state is exactly {0,1}, so 0.9*s - 0.9*(s>0.9) == 0 every step;
//  membranes are recomputed from the constant input current each step).
// Output: d_out = [m_d (2048x1024) | m_e (2048x256)], fp32.

#define BK 32
#define PAD 4

template <int BM, int BN, int TM, int TN>
__global__ __launch_bounds__(256) void gemm_f32(
    const float* __restrict__ A,   // M x K row-major
    const float* __restrict__ B,   // K x N row-major
    float* __restrict__ C,         // M x N row-major
    int M, int N, int K)
{
    static_assert((BM / TM) * (BN / TN) == 256, "256 threads");
    __shared__ float As[BK][BM + PAD];   // transposed A tile: As[k][m]
    __shared__ float Bs[BK][BN + PAD];   // Bs[k][n]

    const int t = threadIdx.x;
    const int brow = blockIdx.y * BM;
    const int bcol = blockIdx.x * BN;

    constexpr int NTX = BN / TN;         // threads along N
    const int tx = t % NTX;
    const int ty = t / NTX;

    float acc[TM][TN];
    #pragma unroll
    for (int i = 0; i < TM; ++i)
        #pragma unroll
        for (int j = 0; j < TN; ++j) acc[i][j] = 0.f;

    for (int k0 = 0; k0 < K; k0 += BK) {
        // ---- stage A tile (BM x BK), transposed into As[k][m] ----
        #pragma unroll
        for (int v = t; v < BM * BK / 4; v += 256) {
            const int row = v / (BK / 4);
            const int kv  = v % (BK / 4);
            const float4 val =
                *(const float4*)&A[(size_t)(brow + row) * K + k0 + kv * 4];
            As[kv * 4 + 0][row] = val.x;
            As[kv * 4 + 1][row] = val.y;
            As[kv * 4 + 2][row] = val.z;
            As[kv * 4 + 3][row] = val.w;
        }
        // ---- stage B tile (BK x BN) ----
        #pragma unroll
        for (int v = t; v < BK * BN / 4; v += 256) {
            const int kk = v / (BN / 4);
            const int cv = v % (BN / 4);
            *(float4*)&Bs[kk][cv * 4] =
                *(const float4*)&B[(size_t)(k0 + kk) * N + bcol + cv * 4];
        }
        __syncthreads();

        #pragma unroll
        for (int k = 0; k < BK; ++k) {
            float a[TM], b[TN];
            #pragma unroll
            for (int i = 0; i < TM; ++i) a[i] = As[k][ty * TM + i];
            #pragma unroll
            for (int j = 0; j < TN; ++j) b[j] = Bs[k][tx * TN + j];
            #pragma unroll
            for (int i = 0; i < TM; ++i)
                #pragma unroll
                for (int j = 0; j < TN; ++j)
                    acc[i][j] = fmaf(a[i], b[j], acc[i][j]);
        }
        __syncthreads();
    }

    // ---- write C ----
    #pragma unroll
    for (int i = 0; i < TM; ++i) {
        #pragma unroll
        for (int j = 0; j < TN; ++j) {
            C[(size_t)(brow + ty * TM + i) * N + bcol + tx * TN + j] = acc[i][j];
        }
    }
}

extern "C" void kernel_launch(void* const* d_in, const int* in_sizes, int n_in,
                              void* d_out, int out_size, void* d_ws, size_t ws_size,
                              hipStream_t stream) {
    const float* x     = (const float*)d_in[0];  // [2048, 1024]
    const float* enc_w = (const float*)d_in[1];  // [1024, 256]
    const float* dec_w = (const float*)d_in[2];  // [256, 1024]

    const int B = 2048, D = 1024, H = 256;

    float* m_d = (float*)d_out;                      // [B, D] at offset 0
    float* m_e = (float*)d_out + (size_t)B * D;      // [B, H] after m_d

    dim3 blk(256);

    // m_e = x @ enc_w   (M=2048, N=256, K=1024) — BN=32 -> 256 blocks
    {
        dim3 grid(H / 32, B / 64);
        gemm_f32<64, 32, 4, 2><<<grid, blk, 0, stream>>>(x, enc_w, m_e, B, H, D);
    }
    // m_d = m_e @ dec_w (M=2048, N=1024, K=256) — BN=64 -> 512 blocks
    {
        dim3 grid(D / 64, B / 64);
        gemm_f32<64, 64, 4, 4><<<grid, blk, 0, stream>>>(m_e, dec_w, m_d, B, D, H);
    }
}

// Round 2
// 32.131 us; speedup vs baseline: 2.6141x; 2.6141x over previous
//
#include <hip/hip_runtime.h>

// SNN autoencoder collapses to: m_e = x @ enc_w ; m_d = m_e @ dec_w
// (spike state is exactly {0,1}, so 0.9*s - 0.9*(s>0.9) == 0 every step;
//  membranes are recomputed from the constant input current each step).
// Output: d_out = [m_d (2048x1024) | m_e (2048x256)], fp32.
//
// bf16 MFMA path: cvt x -> bf16 [M][K]; enc_w,dec_w -> bf16 transposed [N][K];
// GEMM1 writes m_e (f32 out) + m_e_bf (ws, feeds GEMM2). Both GEMMs:
// global_load_lds w16 staging, XOR chunk swizzle (rule #21), LDS double-buffer.

typedef __attribute__((ext_vector_type(8))) short bf16x8;
typedef __attribute__((ext_vector_type(4))) float f32x4;
typedef __attribute__((ext_vector_type(8))) unsigned short ushort8;

__device__ __forceinline__ unsigned short f2bf(float f) {
    unsigned u = __builtin_bit_cast(unsigned, f);
    unsigned r = u + 0x7FFFu + ((u >> 16) & 1u);   // RNE
    return (unsigned short)(r >> 16);
}

// ---- stage ROWS x 64 bf16 tile into LDS via global_load_lds (16B/lane) ----
// LDS layout: linear [row][64] (row stride 128B). Source chunk pre-swizzled
// with chunk ^= (row & 7) so a swizzled ds_read sees global (row, chunk).
template <int ROWS>
__device__ __forceinline__ void stage_tile(const unsigned short* __restrict__ g,
                                           int ld, unsigned short* lds, int t) {
    #pragma unroll
    for (int c = 0; c < ROWS / 32; ++c) {
        const int idx = c * 256 + t;          // 16B-chunk index in tile
        const int row = idx >> 3;             // 8 chunks per row
        const int chunk = (idx & 7) ^ (row & 7);
        const unsigned short* src = g + (size_t)row * ld + chunk * 8;
        unsigned short* dst = lds + (size_t)(idx & ~63) * 8;  // wave-uniform base
        __builtin_amdgcn_global_load_lds(
            (const __attribute__((address_space(1))) void*)src,
            (__attribute__((address_space(3))) void*)dst, 16, 0, 0);
    }
}

template <int BM, int BN, bool WBF>
__global__ __launch_bounds__(256) void mfma_gemm(
    const unsigned short* __restrict__ A,   // [M][K] bf16
    const unsigned short* __restrict__ B,   // [N][K] bf16 (pre-transposed)
    float* __restrict__ C,                  // [M][N] f32
    unsigned short* __restrict__ Cbf,       // [M][N] bf16 (optional)
    int M, int N, int K)
{
    constexpr int BK = 64;
    constexpr int WM = BM / 2, WN = BN / 2;
    constexpr int FM = WM / 16, FN = WN / 16;
    __shared__ __align__(16) unsigned short As[2][BM * BK];
    __shared__ __align__(16) unsigned short Bs[2][BN * BK];

    const int t = threadIdx.x;
    const int lane = t & 63;
    const int l15 = lane & 15, l4 = lane >> 4;
    const int wid = t >> 6;
    const int wr = wid >> 1, wc = wid & 1;      // 2x2 wave grid
    const int brow = blockIdx.y * BM, bcol = blockIdx.x * BN;

    f32x4 acc[FM][FN];
    #pragma unroll
    for (int i = 0; i < FM; ++i)
        #pragma unroll
        for (int j = 0; j < FN; ++j) acc[i][j] = {0.f, 0.f, 0.f, 0.f};

    const unsigned short* Ab = A + (size_t)brow * K;
    const unsigned short* Bb = B + (size_t)bcol * K;
    const int NT = K / BK;

    stage_tile<BM>(Ab, K, As[0], t);
    stage_tile<BN>(Bb, K, Bs[0], t);
    int cur = 0;
    for (int kt = 0; kt < NT; ++kt) {
        __syncthreads();   // drains vmcnt: buf[cur] ready; buffers safe to overwrite
        if (kt + 1 < NT) {
            stage_tile<BM>(Ab + (kt + 1) * BK, K, As[cur ^ 1], t);
            stage_tile<BN>(Bb + (kt + 1) * BK, K, Bs[cur ^ 1], t);
        }
        #pragma unroll
        for (int s = 0; s < 2; ++s) {           // two 32-k MFMA steps per tile
            bf16x8 aF[FM], bF[FN];
            #pragma unroll
            for (int i = 0; i < FM; ++i) {
                const int r = wr * WM + i * 16 + l15;
                const int ch = (s * 4 + l4) ^ (r & 7);
                aF[i] = *(const bf16x8*)&As[cur][r * BK + ch * 8];
            }
            #pragma unroll
            for (int j = 0; j < FN; ++j) {
                const int r = wc * WN + j * 16 + l15;
                const int ch = (s * 4 + l4) ^ (r & 7);
                bF[j] = *(const bf16x8*)&Bs[cur][r * BK + ch * 8];
            }
            #pragma unroll
            for (int i = 0; i < FM; ++i)
                #pragma unroll
                for (int j = 0; j < FN; ++j)
                    acc[i][j] = __builtin_amdgcn_mfma_f32_16x16x32_bf16(
                        aF[i], bF[j], acc[i][j], 0, 0, 0);
        }
        cur ^= 1;
    }

    #pragma unroll
    for (int i = 0; i < FM; ++i)
        #pragma unroll
        for (int j = 0; j < FN; ++j)
            #pragma unroll
            for (int reg = 0; reg < 4; ++reg) {
                const int row = brow + wr * WM + i * 16 + l4 * 4 + reg;
                const int col = bcol + wc * WN + j * 16 + l15;
                const float v = acc[i][j][reg];
                C[(size_t)row * N + col] = v;
                if (WBF) Cbf[(size_t)row * N + col] = f2bf(v);
            }
}

// ---- f32 -> bf16 straight copy (8 elems/thread) ----
__global__ __launch_bounds__(256) void cvt_kernel(const float* __restrict__ in,
                                                  unsigned short* __restrict__ out,
                                                  int n8) {
    const int i = blockIdx.x * blockDim.x + threadIdx.x;
    if (i < n8) {
        float4 a = ((const float4*)in)[2 * i];
        float4 b = ((const float4*)in)[2 * i + 1];
        ushort8 v;
        v[0] = f2bf(a.x); v[1] = f2bf(a.y); v[2] = f2bf(a.z); v[3] = f2bf(a.w);
        v[4] = f2bf(b.x); v[5] = f2bf(b.y); v[6] = f2bf(b.z); v[7] = f2bf(b.w);
        ((ushort8*)out)[i] = v;
    }
}

// ---- f32 [R][C] -> bf16 [C][R] transpose ----
__global__ __launch_bounds__(256) void transpose_cvt(const float* __restrict__ in,
                                                     unsigned short* __restrict__ out,
                                                     int R, int C) {
    __shared__ unsigned short tile[32][33];
    const int r0 = blockIdx.y * 32, c0 = blockIdx.x * 32;
    const int tx = threadIdx.x, ty = threadIdx.y;   // 32 x 8
    #pragma unroll
    for (int k = 0; k < 4; ++k) {
        const int lr = ty + k * 8;
        tile[lr][tx] = f2bf(in[(size_t)(r0 + lr) * C + c0 + tx]);
    }
    __syncthreads();
    #pragma unroll
    for (int k = 0; k < 4; ++k) {
        const int lc = ty + k * 8;
        out[(size_t)(c0 + lc) * R + r0 + tx] = tile[tx][lc];
    }
}

// ---------------- fp32 fallback (round-1 kernel) ----------------
#define BKF 32
#define PADF 4
template <int BM, int BN, int TM, int TN>
__global__ __launch_bounds__(256) void gemm_f32(
    const float* __restrict__ A, const float* __restrict__ B,
    float* __restrict__ C, int M, int N, int K)
{
    __shared__ float As[BKF][BM + PADF];
    __shared__ float Bs[BKF][BN + PADF];
    const int t = threadIdx.x;
    const int brow = blockIdx.y * BM, bcol = blockIdx.x * BN;
    constexpr int NTX = BN / TN;
    const int tx = t % NTX, ty = t / NTX;
    float acc[TM][TN];
    #pragma unroll
    for (int i = 0; i < TM; ++i)
        #pragma unroll
        for (int j = 0; j < TN; ++j) acc[i][j] = 0.f;
    for (int k0 = 0; k0 < K; k0 += BKF) {
        #pragma unroll
        for (int v = t; v < BM * BKF / 4; v += 256) {
            const int row = v / (BKF / 4), kv = v % (BKF / 4);
            const float4 val = *(const float4*)&A[(size_t)(brow + row) * K + k0 + kv * 4];
            As[kv * 4 + 0][row] = val.x; As[kv * 4 + 1][row] = val.y;
            As[kv * 4 + 2][row] = val.z; As[kv * 4 + 3][row] = val.w;
        }
        #pragma unroll
        for (int v = t; v < BKF * BN / 4; v += 256) {
            const int kk = v / (BN / 4), cv = v % (BN / 4);
            *(float4*)&Bs[kk][cv * 4] = *(const float4*)&B[(size_t)(k0 + kk) * N + bcol + cv * 4];
        }
        __syncthreads();
        #pragma unroll
        for (int k = 0; k < BKF; ++k) {
            float a[TM], b[TN];
            #pragma unroll
            for (int i = 0; i < TM; ++i) a[i] = As[k][ty * TM + i];
            #pragma unroll
            for (int j = 0; j < TN; ++j) b[j] = Bs[k][tx * TN + j];
            #pragma unroll
            for (int i = 0; i < TM; ++i)
                #pragma unroll
                for (int j = 0; j < TN; ++j) acc[i][j] = fmaf(a[i], b[j], acc[i][j]);
        }
        __syncthreads();
    }
    #pragma unroll
    for (int i = 0; i < TM; ++i)
        #pragma unroll
        for (int j = 0; j < TN; ++j)
            C[(size_t)(brow + ty * TM + i) * N + bcol + tx * TN + j] = acc[i][j];
}

extern "C" void kernel_launch(void* const* d_in, const int* in_sizes, int n_in,
                              void* d_out, int out_size, void* d_ws, size_t ws_size,
                              hipStream_t stream) {
    const float* x     = (const float*)d_in[0];  // [2048, 1024]
    const float* enc_w = (const float*)d_in[1];  // [1024, 256]
    const float* dec_w = (const float*)d_in[2];  // [256, 1024]

    const int B = 2048, D = 1024, H = 256;
    float* m_d = (float*)d_out;
    float* m_e = (float*)d_out + (size_t)B * D;

    const size_t need = (size_t)B * D * 2      // x_bf
                      + (size_t)D * H * 2      // enc_wT
                      + (size_t)H * D * 2      // dec_wT
                      + (size_t)B * H * 2;     // m_e bf16
    if (ws_size >= need) {
        unsigned short* x_bf  = (unsigned short*)d_ws;            // [2048][1024]
        unsigned short* encT  = x_bf + (size_t)B * D;             // [256][1024]
        unsigned short* decT  = encT + (size_t)H * D;             // [1024][256]
        unsigned short* me_bf = decT + (size_t)D * H;             // [2048][256]

        cvt_kernel<<<dim3((B * D / 8 + 255) / 256), dim3(256), 0, stream>>>(x, x_bf, B * D / 8);
        transpose_cvt<<<dim3(H / 32, D / 32), dim3(32, 8), 0, stream>>>(enc_w, encT, D, H);
        transpose_cvt<<<dim3(D / 32, H / 32), dim3(32, 8), 0, stream>>>(dec_w, decT, H, D);

        // m_e = x @ enc_w : M=2048 N=256 K=1024, 64x32 tiles -> 256 blocks
        mfma_gemm<64, 32, true><<<dim3(H / 32, B / 64), dim3(256), 0, stream>>>(
            x_bf, encT, m_e, me_bf, B, H, D);
        // m_d = m_e @ dec_w : M=2048 N=1024 K=256, 64x64 tiles -> 512 blocks
        mfma_gemm<64, 64, false><<<dim3(D / 64, B / 64), dim3(256), 0, stream>>>(
            me_bf, decT, m_d, nullptr, B, D, H);
    } else {
        // fp32 fallback
        gemm_f32<64, 32, 4, 2><<<dim3(H / 32, B / 64), dim3(256), 0, stream>>>(x, enc_w, m_e, B, H, D);
        gemm_f32<64, 64, 4, 4><<<dim3(D / 64, B / 64), dim3(256), 0, stream>>>(m_e, dec_w, m_d, B, D, H);
    }
}

// Round 3
// 26.360 us; speedup vs baseline: 3.1864x; 1.2189x over previous
//
#include <hip/hip_runtime.h>

// SNN autoencoder collapses to: m_e = x @ enc_w ; m_d = m_e @ dec_w
// (spike state is exactly {0,1}, so 0.9*s - 0.9*(s>0.9) == 0 every step;
//  membranes are recomputed from the constant input current each step).
// Output: d_out = [m_d (2048x1024) | m_e (2048x256)], fp32.
//
// 3 dispatches:
//   prep  : x->bf16, enc->bf16 transposed [N][K], dec->bf16 transposed [N][K]
//   gemm1 : m_e = x @ enc_w   (32x32 tiles, 512 blocks, dbuf K-loop)
//   gemm2 : m_d = m_e @ dec_w (K=256 LDS-resident, 1 barrier, 1024 blocks)

typedef __attribute__((ext_vector_type(8))) short bf16x8;
typedef __attribute__((ext_vector_type(4))) float f32x4;
typedef __attribute__((ext_vector_type(8))) unsigned short ushort8;

__device__ __forceinline__ unsigned short f2bf(float f) {
    unsigned u = __builtin_bit_cast(unsigned, f);
    unsigned r = u + 0x7FFFu + ((u >> 16) & 1u);   // RNE
    return (unsigned short)(r >> 16);
}

// ---- stage ROWS x 64 bf16 tile into LDS via global_load_lds (16B/lane) ----
// LDS layout: linear [row][64] (row stride 128B). Source chunk pre-swizzled
// with chunk ^= (row & 7); swizzled ds_read sees global (row, chunk). (rule #21)
template <int ROWS>
__device__ __forceinline__ void stage_tile(const unsigned short* __restrict__ g,
                                           int ld, unsigned short* lds, int t) {
    #pragma unroll
    for (int c = 0; c < ROWS / 32; ++c) {
        const int idx = c * 256 + t;          // 16B-chunk index in tile
        const int row = idx >> 3;             // 8 chunks per row
        const int chunk = (idx & 7) ^ (row & 7);
        const unsigned short* src = g + (size_t)row * ld + chunk * 8;
        unsigned short* dst = lds + (size_t)(idx & ~63) * 8;  // wave-uniform base
        __builtin_amdgcn_global_load_lds(
            (const __attribute__((address_space(1))) void*)src,
            (__attribute__((address_space(3))) void*)dst, 16, 0, 0);
    }
}

// ---------------- GEMM1: K-loop, double-buffered ----------------
template <int BM, int BN, bool WBF>
__global__ __launch_bounds__(256) void mfma_gemm(
    const unsigned short* __restrict__ A,   // [M][K] bf16
    const unsigned short* __restrict__ B,   // [N][K] bf16 (pre-transposed)
    float* __restrict__ C,                  // [M][N] f32
    unsigned short* __restrict__ Cbf,       // [M][N] bf16 (optional)
    int M, int N, int K)
{
    constexpr int BK = 64;
    constexpr int WM = BM / 2, WN = BN / 2;
    constexpr int FM = WM / 16, FN = WN / 16;
    __shared__ __align__(16) unsigned short As[2][BM * BK];
    __shared__ __align__(16) unsigned short Bs[2][BN * BK];

    const int t = threadIdx.x;
    const int lane = t & 63;
    const int l15 = lane & 15, l4 = lane >> 4;
    const int wid = t >> 6;
    const int wr = wid >> 1, wc = wid & 1;      // 2x2 wave grid
    const int brow = blockIdx.y * BM, bcol = blockIdx.x * BN;

    f32x4 acc[FM][FN];
    #pragma unroll
    for (int i = 0; i < FM; ++i)
        #pragma unroll
        for (int j = 0; j < FN; ++j) acc[i][j] = {0.f, 0.f, 0.f, 0.f};

    const unsigned short* Ab = A + (size_t)brow * K;
    const unsigned short* Bb = B + (size_t)bcol * K;
    const int NT = K / BK;

    stage_tile<BM>(Ab, K, As[0], t);
    stage_tile<BN>(Bb, K, Bs[0], t);
    int cur = 0;
    for (int kt = 0; kt < NT; ++kt) {
        __syncthreads();   // drains vmcnt: buf[cur] ready; prev reads of buf[cur^1] done
        if (kt + 1 < NT) {
            stage_tile<BM>(Ab + (kt + 1) * BK, K, As[cur ^ 1], t);
            stage_tile<BN>(Bb + (kt + 1) * BK, K, Bs[cur ^ 1], t);
        }
        #pragma unroll
        for (int s = 0; s < 2; ++s) {
            bf16x8 aF[FM], bF[FN];
            #pragma unroll
            for (int i = 0; i < FM; ++i) {
                const int r = wr * WM + i * 16 + l15;
                const int ch = (s * 4 + l4) ^ (r & 7);
                aF[i] = *(const bf16x8*)&As[cur][r * BK + ch * 8];
            }
            #pragma unroll
            for (int j = 0; j < FN; ++j) {
                const int r = wc * WN + j * 16 + l15;
                const int ch = (s * 4 + l4) ^ (r & 7);
                bF[j] = *(const bf16x8*)&Bs[cur][r * BK + ch * 8];
            }
            #pragma unroll
            for (int i = 0; i < FM; ++i)
                #pragma unroll
                for (int j = 0; j < FN; ++j)
                    acc[i][j] = __builtin_amdgcn_mfma_f32_16x16x32_bf16(
                        aF[i], bF[j], acc[i][j], 0, 0, 0);
        }
        cur ^= 1;
    }

    #pragma unroll
    for (int i = 0; i < FM; ++i)
        #pragma unroll
        for (int j = 0; j < FN; ++j)
            #pragma unroll
            for (int reg = 0; reg < 4; ++reg) {
                const int row = brow + wr * WM + i * 16 + l4 * 4 + reg;
                const int col = bcol + wc * WN + j * 16 + l15;
                const float v = acc[i][j][reg];
                C[(size_t)row * N + col] = v;
                if (WBF) Cbf[(size_t)row * N + col] = f2bf(v);
            }
}

// ---------------- GEMM2: K=256 LDS-resident, single barrier ----------------
// BM=32, BN=64, 4 waves (2x2): WM=16, WN=32 (FM=1, FN=2). grid 16x64 = 1024.
__global__ __launch_bounds__(256) void gemm2_kres(
    const unsigned short* __restrict__ A,   // [2048][256] bf16 (m_e)
    const unsigned short* __restrict__ B,   // [1024][256] bf16 (decT)
    float* __restrict__ C)                  // [2048][1024] f32 (m_d)
{
    constexpr int K = 256, N = 1024;
    __shared__ __align__(16) unsigned short As[4][32 * 64];  // 16 KB
    __shared__ __align__(16) unsigned short Bs[4][64 * 64];  // 32 KB

    const int t = threadIdx.x;
    const int lane = t & 63;
    const int l15 = lane & 15, l4 = lane >> 4;
    const int wid = t >> 6;
    const int wr = wid >> 1, wc = wid & 1;
    const int brow = blockIdx.y * 32, bcol = blockIdx.x * 64;

    #pragma unroll
    for (int kt = 0; kt < 4; ++kt) {
        stage_tile<32>(A + (size_t)brow * K + kt * 64, K, As[kt], t);
        stage_tile<64>(B + (size_t)bcol * K + kt * 64, K, Bs[kt], t);
    }
    __syncthreads();

    f32x4 acc[2] = {{0.f, 0.f, 0.f, 0.f}, {0.f, 0.f, 0.f, 0.f}};
    #pragma unroll
    for (int kt = 0; kt < 4; ++kt)
        #pragma unroll
        for (int s = 0; s < 2; ++s) {
            const int ra = wr * 16 + l15;
            const int cha = (s * 4 + l4) ^ (ra & 7);
            bf16x8 aF = *(const bf16x8*)&As[kt][ra * 64 + cha * 8];
            #pragma unroll
            for (int j = 0; j < 2; ++j) {
                const int rb = wc * 32 + j * 16 + l15;
                const int chb = (s * 4 + l4) ^ (rb & 7);
                bf16x8 bF = *(const bf16x8*)&Bs[kt][rb * 64 + chb * 8];
                acc[j] = __builtin_amdgcn_mfma_f32_16x16x32_bf16(aF, bF, acc[j], 0, 0, 0);
            }
        }

    #pragma unroll
    for (int j = 0; j < 2; ++j)
        #pragma unroll
        for (int reg = 0; reg < 4; ++reg) {
            const int row = brow + wr * 16 + l4 * 4 + reg;
            const int col = bcol + wc * 32 + j * 16 + l15;
            C[(size_t)row * N + col] = acc[j][reg];
        }
}

// ---------------- fused prep: x->bf16 | enc transpose | dec transpose ----------
__global__ __launch_bounds__(256) void prep(
    const float* __restrict__ x, const float* __restrict__ enc,
    const float* __restrict__ dec, unsigned short* __restrict__ x_bf,
    unsigned short* __restrict__ encT, unsigned short* __restrict__ decT)
{
    __shared__ unsigned short tile[32][33];
    const int bid = blockIdx.x;
    const int t = threadIdx.x;

    if (bid < 1024) {               // ---- x cvt: 2M elems, 8/thread ----
        const int i = bid * 256 + t;
        float4 a = ((const float4*)x)[2 * i];
        float4 b = ((const float4*)x)[2 * i + 1];
        ushort8 v;
        v[0] = f2bf(a.x); v[1] = f2bf(a.y); v[2] = f2bf(a.z); v[3] = f2bf(a.w);
        v[4] = f2bf(b.x); v[5] = f2bf(b.y); v[6] = f2bf(b.z); v[7] = f2bf(b.w);
        ((ushort8*)x_bf)[i] = v;
        return;
    }
    const float* in; unsigned short* out; int R, C, bx, by;
    if (bid < 1280) {               // ---- enc [1024][256] -> encT [256][1024] ----
        const int bb = bid - 1024;
        in = enc; out = encT; R = 1024; C = 256; bx = bb % 8; by = bb / 8;
    } else {                        // ---- dec [256][1024] -> decT [1024][256] ----
        const int bb = bid - 1280;
        in = dec; out = decT; R = 256; C = 1024; bx = bb % 32; by = bb / 32;
    }
    const int r0 = by * 32, c0 = bx * 32;
    const int tx = t % 32, ty = t / 32;       // 32 x 8
    #pragma unroll
    for (int k = 0; k < 4; ++k) {
        const int lr = ty + k * 8;
        tile[lr][tx] = f2bf(in[(size_t)(r0 + lr) * C + c0 + tx]);
    }
    __syncthreads();
    #pragma unroll
    for (int k = 0; k < 4; ++k) {
        const int lc = ty + k * 8;
        out[(size_t)(c0 + lc) * R + r0 + tx] = tile[tx][lc];
    }
}

// ---------------- fp32 fallback ----------------
#define BKF 32
#define PADF 4
template <int BM, int BN, int TM, int TN>
__global__ __launch_bounds__(256) void gemm_f32(
    const float* __restrict__ A, const float* __restrict__ B,
    float* __restrict__ C, int M, int N, int K)
{
    __shared__ float As[BKF][BM + PADF];
    __shared__ float Bs[BKF][BN + PADF];
    const int t = threadIdx.x;
    const int brow = blockIdx.y * BM, bcol = blockIdx.x * BN;
    constexpr int NTX = BN / TN;
    const int tx = t % NTX, ty = t / NTX;
    float acc[TM][TN];
    #pragma unroll
    for (int i = 0; i < TM; ++i)
        #pragma unroll
        for (int j = 0; j < TN; ++j) acc[i][j] = 0.f;
    for (int k0 = 0; k0 < K; k0 += BKF) {
        #pragma unroll
        for (int v = t; v < BM * BKF / 4; v += 256) {
            const int row = v / (BKF / 4), kv = v % (BKF / 4);
            const float4 val = *(const float4*)&A[(size_t)(brow + row) * K + k0 + kv * 4];
            As[kv * 4 + 0][row] = val.x; As[kv * 4 + 1][row] = val.y;
            As[kv * 4 + 2][row] = val.z; As[kv * 4 + 3][row] = val.w;
        }
        #pragma unroll
        for (int v = t; v < BKF * BN / 4; v += 256) {
            const int kk = v / (BN / 4), cv = v % (BN / 4);
            *(float4*)&Bs[kk][cv * 4] = *(const float4*)&B[(size_t)(k0 + kk) * N + bcol + cv * 4];
        }
        __syncthreads();
        #pragma unroll
        for (int k = 0; k < BKF; ++k) {
            float a[TM], b[TN];
            #pragma unroll
            for (int i = 0; i < TM; ++i) a[i] = As[k][ty * TM + i];
            #pragma unroll
            for (int j = 0; j < TN; ++j) b[j] = Bs[k][tx * TN + j];
            #pragma unroll
            for (int i = 0; i < TM; ++i)
                #pragma unroll
                for (int j = 0; j < TN; ++j) acc[i][j] = fmaf(a[i], b[j], acc[i][j]);
        }
        __syncthreads();
    }
    #pragma unroll
    for (int i = 0; i < TM; ++i)
        #pragma unroll
        for (int j = 0; j < TN; ++j)
            C[(size_t)(brow + ty * TM + i) * N + bcol + tx * TN + j] = acc[i][j];
}

extern "C" void kernel_launch(void* const* d_in, const int* in_sizes, int n_in,
                              void* d_out, int out_size, void* d_ws, size_t ws_size,
                              hipStream_t stream) {
    const float* x     = (const float*)d_in[0];  // [2048, 1024]
    const float* enc_w = (const float*)d_in[1];  // [1024, 256]
    const float* dec_w = (const float*)d_in[2];  // [256, 1024]

    const int B = 2048, D = 1024, H = 256;
    float* m_d = (float*)d_out;
    float* m_e = (float*)d_out + (size_t)B * D;

    const size_t need = (size_t)B * D * 2 + (size_t)D * H * 2
                      + (size_t)H * D * 2 + (size_t)B * H * 2;
    if (ws_size >= need) {
        unsigned short* x_bf  = (unsigned short*)d_ws;            // [2048][1024]
        unsigned short* encT  = x_bf + (size_t)B * D;             // [256][1024]
        unsigned short* decT  = encT + (size_t)H * D;             // [1024][256]
        unsigned short* me_bf = decT + (size_t)D * H;             // [2048][256]

        prep<<<dim3(1536), dim3(256), 0, stream>>>(x, enc_w, dec_w, x_bf, encT, decT);

        // m_e = x @ enc_w : M=2048 N=256 K=1024, 32x32 tiles -> 512 blocks
        mfma_gemm<32, 32, true><<<dim3(H / 32, B / 32), dim3(256), 0, stream>>>(
            x_bf, encT, m_e, me_bf, B, H, D);
        // m_d = m_e @ dec_w : K-resident, 32x64 tiles -> 1024 blocks
        gemm2_kres<<<dim3(D / 64, B / 32), dim3(256), 0, stream>>>(me_bf, decT, m_d);
    } else {
        gemm_f32<64, 32, 4, 2><<<dim3(H / 32, B / 64), dim3(256), 0, stream>>>(x, enc_w, m_e, B, H, D);
        gemm_f32<64, 64, 4, 4><<<dim3(D / 64, B / 64), dim3(256), 0, stream>>>(m_e, dec_w, m_d, B, D, H);
    }
}